// Round 8
// baseline (234.287 us; speedup 1.0000x reference)
//
#include <hip/hip_runtime.h>
#include <stdint.h>

#define AS1 __attribute__((address_space(1)))
#define AS3 __attribute__((address_space(3)))

typedef int v4i __attribute__((ext_vector_type(4)));

// Problem constants (from reference)
constexpr int G = 7, B = 8, M = 512, N = 512, K = 1024;
constexpr int GBn = G * B;                       // 56
// X_ZP = -66, Y_ZP = 160.  With y' = y - 128:
//   sum (x-X)(y-Y) = dot_i8(x, y') - 32*rowsum_x + 66*colsum_y' - 2162688

// ws layout: yt + colsum only (x8 pass eliminated; x is read once by the GEMM)
constexpr size_t YT_BYTES = (size_t)B * N * K;   // 4,194,304  yt[b][n][k] i8 (y-128)
constexpr size_t CS_CNT   = (size_t)B * N;       // 4,096 colsums
constexpr size_t WS_NEEDED = YT_BYTES + CS_CNT * 4;

// ---------------------------------------------------------------------------
// K0: zero colsum (4096 ints) so K1 can atomicAdd into it.
// ---------------------------------------------------------------------------
__global__ __launch_bounds__(256) void zero_colsum(int* __restrict__ cs) {
    cs[blockIdx.x * 256 + threadIdx.x] = 0;
}

// ---------------------------------------------------------------------------
// K1: transpose + pack y -> yt[b][n][k] i8 (y-128), and fold colsum(y') in via
// per-block partial sums + atomics. Grid: (N/64, K/64, B), block 256.
// ---------------------------------------------------------------------------
__global__ __launch_bounds__(256) void transpose_pack_y(const int* __restrict__ y,
                                                        signed char* __restrict__ yt,
                                                        int* __restrict__ colsum) {
    __shared__ unsigned char tile[64][80];
    int n0 = blockIdx.x * 64;
    int k0 = blockIdx.y * 64;
    int b  = blockIdx.z;
    int t  = threadIdx.x;

    int r  = t >> 2;
    int c0 = (t & 3) * 16;
    const int* src = y + ((size_t)b * K + k0 + r) * N + n0 + c0;
    uint32_t p[4];
#pragma unroll
    for (int q = 0; q < 4; ++q) {
        int4 v = ((const int4*)src)[q];
        p[q] =  (uint32_t)((v.x & 255) ^ 128)
             | ((uint32_t)((v.y & 255) ^ 128) << 8)
             | ((uint32_t)((v.z & 255) ^ 128) << 16)
             | ((uint32_t)((v.w & 255) ^ 128) << 24);
    }
    *(uint4*)&tile[r][c0] = make_uint4(p[0], p[1], p[2], p[3]);
    __syncthreads();

    int nl = t >> 2;
    int kc = (t & 3) * 16;
    uint32_t q[4];
#pragma unroll
    for (int w = 0; w < 4; ++w) {
        uint32_t b0 = tile[kc + w * 4 + 0][nl];
        uint32_t b1 = tile[kc + w * 4 + 1][nl];
        uint32_t b2 = tile[kc + w * 4 + 2][nl];
        uint32_t b3 = tile[kc + w * 4 + 3][nl];
        q[w] = b0 | (b1 << 8) | (b2 << 16) | (b3 << 24);
    }
    *(uint4*)(yt + ((size_t)b * N + n0 + nl) * K + k0 + kc) = make_uint4(q[0], q[1], q[2], q[3]);

    // colsum partial: this thread holds 16 k-bytes of column (n0+nl)
    int s = 0;
#pragma unroll
    for (int w = 0; w < 4; ++w) {
        uint32_t v = q[w];
        s += (int)(signed char)(v) + (int)(signed char)(v >> 8)
           + (int)(signed char)(v >> 16) + (int)(signed char)(v >> 24);
    }
    s += __shfl_down(s, 1, 64);
    s += __shfl_down(s, 2, 64);
    if ((t & 3) == 0) atomicAdd(&colsum[b * N + n0 + nl], s);
}

// ---------------------------------------------------------------------------
// K2: fused pack+GEMM, x read ONCE, zero k-loop barriers.
// Block = 64m x 512n (full N) for one (g,b). 512 thr = 8 waves, each 64m x 64n
// (4x4 of 16x16x64 i8 MFMA, acc 64 VGPR).
// Phase A: stream 64 rows x 4KB int32 x -> pack -> A_lds[64][1024] i8
//   (XOR slot swizzle: phys 16B slot p of row r holds logical slot p ^ (r&7);
//   bank-load balanced for both b128 writes and quad reads) + rowsum. 1 barrier.
// Phase B: 16 k-steps, fully unrolled, NO barriers:
//   A-frags via ds_read_b128 from A_lds; B-frags via global dwordx4 from yt
//   (L2-resident 4MB); compiler-managed fine-grained vmcnt/lgkmcnt (the thing
//   it is measured to do well — m97/m131), MFMA-latency-hidden by 16 waves/CU.
// Grid: (M/64=8, 56) = 448 blocks, 2 blocks/CU (LDS 64.3KB, VGPR<=128).
// ---------------------------------------------------------------------------
__global__ __launch_bounds__(512, 4) void gemm_fused(const int* __restrict__ x,
                                                     const signed char* __restrict__ yt,
                                                     const int* __restrict__ colsum,
                                                     const float* __restrict__ xsp,
                                                     const float* __restrict__ ysp,
                                                     float* __restrict__ out) {
    __shared__ signed char A[64 * 1024];      // [m][k], slot-swizzled, 64KB
    __shared__ int rsm[64];

    int mt = blockIdx.x;                      // 0..7
    int gb = blockIdx.y;                      // 0..55
    int b  = gb & 7;
    int t  = threadIdx.x;

    // ---- phase A: pack x m-stripe into LDS + rowsum ----
    {
        int r = t >> 3;                       // row 0..63
        int c = t & 7;                        // 128-int chunk
        const int* xr = x + ((size_t)(gb * M + mt * 64 + r)) * K + c * 128;
        int rs = 0;
#pragma unroll
        for (int j = 0; j < 8; ++j) {         // logical slot s = c*8 + j
            uint32_t pw[4];
#pragma unroll
            for (int h = 0; h < 4; ++h) {
                int4 v = ((const int4*)(xr + j * 16))[h];
                rs += v.x + v.y + v.z + v.w;
                pw[h] =  (uint32_t)(v.x & 255) | ((uint32_t)(v.y & 255) << 8)
                      | ((uint32_t)(v.z & 255) << 16) | ((uint32_t)(v.w & 255) << 24);
            }
            int phys = (c * 8 + j) ^ (r & 7);
            *(uint4*)(A + r * 1024 + phys * 16) = make_uint4(pw[0], pw[1], pw[2], pw[3]);
        }
        rs += __shfl_down(rs, 1, 64);
        rs += __shfl_down(rs, 2, 64);
        rs += __shfl_down(rs, 4, 64);
        if (c == 0) rsm[r] = rs;
    }
    __syncthreads();                          // the ONLY barrier

    // ---- phase B: barrier-free K-loop ----
    int w = t >> 6, lane = t & 63;
    int wn = w * 64;                          // 8 waves cover full N=512
    int fr = lane & 15, q = lane >> 4;

    const signed char* Bb = yt + ((size_t)(b * N + wn + fr)) * K + q * 16;

    v4i acc[4][4];
#pragma unroll
    for (int i = 0; i < 4; ++i)
#pragma unroll
        for (int j = 0; j < 4; ++j) acc[i][j] = (v4i){0, 0, 0, 0};

#pragma unroll
    for (int s = 0; s < 16; ++s) {
        v4i bf[4], af[4];
#pragma unroll
        for (int j = 0; j < 4; ++j)
            bf[j] = *(const v4i*)(Bb + (size_t)j * 16 * K + s * 64);
#pragma unroll
        for (int i = 0; i < 4; ++i)
            af[i] = *(const v4i*)(A + (i * 16 + fr) * 1024 + ((s * 4 + q) ^ (fr & 7)) * 16);
#pragma unroll
        for (int i = 0; i < 4; ++i)
#pragma unroll
            for (int j = 0; j < 4; ++j)
                acc[i][j] = __builtin_amdgcn_mfma_i32_16x16x64_i8(af[i], bf[j], acc[i][j], 0, 0, 0);
    }

    // ---- epilogue: C = sc * (dot - 32*rowsum_x + 66*colsum_y' - 2162688) ----
    float sc = xsp[0] * ysp[0];
    int colL = fr;
    int rowQ = q * 4;
    float* outg = out + (size_t)gb * M * N;
    const int* cs = colsum + b * N;
#pragma unroll
    for (int i = 0; i < 4; ++i) {
#pragma unroll
        for (int r = 0; r < 4; ++r) {
            int row_g = mt * 64 + i * 16 + rowQ + r;
            int rsv = rsm[i * 16 + rowQ + r];
#pragma unroll
            for (int j = 0; j < 4; ++j) {
                int col_g = wn + j * 16 + colL;
                int v = acc[i][j][r] - 32 * rsv + 66 * cs[col_g] - 2162688;
                outg[(size_t)row_g * N + col_g] = sc * (float)v;
            }
        }
    }
}

// ---------------------------------------------------------------------------
// Fallback (only if ws_size is too small): naive but correct.
// ---------------------------------------------------------------------------
__global__ __launch_bounds__(256) void naive_kernel(const int* __restrict__ x,
                                                    const int* __restrict__ y,
                                                    const float* __restrict__ xsp,
                                                    const float* __restrict__ ysp,
                                                    float* __restrict__ out) {
    size_t idx = (size_t)blockIdx.x * 256 + threadIdx.x;
    int n  = (int)(idx & 511);
    int m  = (int)((idx >> 9) & 511);
    int gb = (int)(idx >> 18);
    int b  = gb & 7;
    const int* xr = x + ((size_t)gb * M + m) * K;
    const int* yc = y + (size_t)b * K * N + n;
    int dot = 0, sx = 0, sy = 0;
    for (int k = 0; k < K; ++k) {
        int a = xr[k];
        int c = yc[(size_t)k * N];
        dot += a * c; sx += a; sy += c;
    }
    float s = xsp[0] * ysp[0];
    out[idx] = s * (float)(dot - 160 * sx + 66 * sy - 10813440);
}

// ---------------------------------------------------------------------------
extern "C" void kernel_launch(void* const* d_in, const int* in_sizes, int n_in,
                              void* d_out, int out_size, void* d_ws, size_t ws_size,
                              hipStream_t stream) {
    const int*   x  = (const int*)d_in[0];     // [7,8,512,1024] int8 values in int32
    const int*   y  = (const int*)d_in[1];     // [8,1024,512] uint8 values in int32
    const float* xs = (const float*)d_in[2];
    const float* ys = (const float*)d_in[3];
    float* out = (float*)d_out;

    if (ws_size < WS_NEEDED) {
        naive_kernel<<<(14680064 + 255) / 256, 256, 0, stream>>>(x, y, xs, ys, out);
        return;
    }

    char* ws = (char*)d_ws;
    signed char* yt = (signed char*)ws;
    int* colsum = (int*)(ws + YT_BYTES);

    zero_colsum<<<CS_CNT / 256, 256, 0, stream>>>(colsum);
    transpose_pack_y<<<dim3(N / 64, K / 64, B), 256, 0, stream>>>(y, yt, colsum);
    gemm_fused<<<dim3(M / 64, GBn), 512, 0, stream>>>(x, yt, colsum, xs, ys, out);
}